// Round 11
// baseline (711.956 us; speedup 1.0000x reference)
//
#include <hip/hip_runtime.h>
#include <stdint.h>

// HashedEmbeddingBag: out[b][d] = sum_{i<50} weight[(idx[b][i]*P1 + d*P2) % WS]
// WS = 2,000,000; B = 16384; L = 50; D = 128.
//
// R10: single 8-bag merged stream + LDS accumulation via ds_add_f32.
// R9 was VALU-bound (65%): 4-way select accumulate ~9 VALU/entry. Here the
// accumulate is ONE ds_add_f32 into acc[bag][d] (each cell has exactly one
// writer thread -> program-ordered, bit-deterministic; bank = d%32 -> exact
// 2-way per wave = free). With accumulate cost independent of merge width,
// all 8 bags of a group merge into ONE sorted stream: keys (v<<3)|bag
// (x8-scaled; u = K + 8*(c-WS-lo) gives tag u&7, tile entry u>>3).
// Tile 49152 bf16 entries (96KB) -> 41 regions; ext 8x808 (25.9KB);
// acc 32KB. Single-buffer staging (stage -> barrier -> process -> barrier),
// no async overlap with processing (R6-ghost exclusion). bf16 table built
// by a pre-pass kernel into d_ws (RNE; absmax 0.25 << 0.71 threshold).

#define WS       2000000
#define EMB_DIM  128
#define BAG_LEN  50
#define BATCH    16384

#define NBLK     256
#define NTHR     1024
#define BAGS_PB  64
#define TSZ      49152                   // bf16 tile entries (96KB)
#define NREG     41                      // 40 full + last 33,920
#define SBIG     300227u                 // P2 % WS
#define EXT8_N   808                     // 400 + 400 + 8 sentinels
#define SENT     0x7FFFFFFFu

#define GLOAD_LDS16(gp, lp)                                            \
    __builtin_amdgcn_global_load_lds(                                  \
        (const __attribute__((address_space(1))) uint32_t*)(gp),       \
        (__attribute__((address_space(3))) uint32_t*)(lp), 16, 0, 0)

__device__ __forceinline__ uint32_t f2bf(float x) {
    uint32_t u = __float_as_uint(x);
    return (u + 0x7FFFu + ((u >> 16) & 1u)) >> 16;   // RNE
}

// ---- pre-pass: fp32 table -> bf16 into d_ws ----
__global__ __launch_bounds__(1024) void conv_bf16(
    const float* __restrict__ w, uint16_t* __restrict__ o)
{
    const int i = (blockIdx.x * 1024 + threadIdx.x) * 8;
    if (i >= WS) return;
    const float4 f0 = *(const float4*)(w + i);
    const float4 f1 = *(const float4*)(w + i + 4);
    uint4 st;
    st.x = f2bf(f0.x) | (f2bf(f0.y) << 16);
    st.y = f2bf(f0.z) | (f2bf(f0.w) << 16);
    st.z = f2bf(f1.x) | (f2bf(f1.y) << 16);
    st.w = f2bf(f1.z) | (f2bf(f1.w) << 16);
    *(uint4*)(o + i) = st;               // i%8==0 -> 16B aligned
}

__global__ __launch_bounds__(NTHR, 4) void heb_bf16v2(
    const uint16_t* __restrict__ wbf,
    const int*      __restrict__ indices,
    float*          __restrict__ out)
{
    __shared__ __align__(16) uint16_t tile[TSZ];       // 96 KB
    __shared__ float    acc[BAGS_PB * EMB_DIM];        // 32 KB
    __shared__ uint32_t ext8[8][EXT8_N];               // 25.9 KB

    const int tid     = threadIdx.x;
    const int d       = tid & 127;
    const int g       = tid >> 7;          // group 0..7, owns bags 8g..8g+7
    const int bagBase = blockIdx.x * BAGS_PB;

    // sort scratch inside tile (dead before first staging)
    uint32_t* araw = (uint32_t*)&tile[0];          // words [0, 3328)
    uint32_t* S    = (uint32_t*)&tile[0] + 4096;   // words [4096, 7424)

    // ---- phase 0/1: zero acc; sentinel-fill ext; hash a = idx*P1 % WS ----
    for (int p = tid; p < BAGS_PB * EMB_DIM; p += NTHR) acc[p] = 0.0f;
    for (int p = tid; p < 8 * EXT8_N; p += NTHR)
        ((uint32_t*)ext8)[p] = SENT;
    for (int p = tid; p < BAGS_PB * BAG_LEN; p += NTHR) {
        uint32_t b = (uint32_t)p / 50u;
        uint32_t i = (uint32_t)p - b * 50u;
        uint64_t idx = (uint64_t)(uint32_t)indices[bagBase * BAG_LEN + p];
        araw[b * 52 + i] = (uint32_t)((idx * 9824516537ull) % (uint64_t)WS);
    }
    __syncthreads();

    // ---- phase 2a: rank-sort each bag (ties by index) -> S ----
    for (int p = tid; p < BAGS_PB * BAG_LEN; p += NTHR) {
        uint32_t b = (uint32_t)p / 50u;
        uint32_t i = (uint32_t)p - b * 50u;
        uint32_t v = araw[b * 52 + i];
        int rank = 0;
        for (int q = 0; q < BAG_LEN; ++q) {
            uint32_t w = araw[b * 52 + q];
            rank += (w < v || (w == v && q < (int)i)) ? 1 : 0;
        }
        S[b * 52 + rank] = v;
    }
    __syncthreads();

    // ---- phase 2b: 8-way merge per group via rank composition ----
    // merged rank = in-bag rank + Sum_{b2!=b} #{x in T_b2 : x < key};
    // key = v+1 for b2 < b (ties sort below), v for b2 > b. Ranks form a
    // permutation of [0,400) -> every slot written exactly once.
    for (int p = tid; p < BAGS_PB * BAG_LEN; p += NTHR) {
        uint32_t bag = (uint32_t)p / 50u;
        uint32_t i   = (uint32_t)p - bag * 50u;
        uint32_t gg  = bag >> 3, b = bag & 7u;
        uint32_t v = S[bag * 52 + i];
        int r = (int)i;
        for (uint32_t b2 = 0; b2 < 8u; ++b2) {
            if (b2 == b) continue;
            const uint32_t* T = &S[((gg << 3) + b2) * 52];
            uint32_t key = (b2 < b) ? v + 1u : v;
            int lo = 0, hi = 50;
            while (lo < hi) {                  // 6 uniform steps
                int mid = (lo + hi) >> 1;
                bool lt = T[mid] < key;
                lo = lt ? mid + 1 : lo;
                hi = lt ? hi : mid;
            }
            r += lo;
        }
        ext8[gg][r]       = (v << 3) | b;                  // first copy
        ext8[gg][r + 400] = ((v + (uint32_t)WS) << 3) | b; // rotation copy
    }
    __syncthreads();                       // ext final; S/araw dead

    // ---- phase 3: per-thread stream init (one 400-entry stream) ----
    const uint32_t c  = ((uint32_t)d * SBIG) % (uint32_t)WS;
    const uint32_t C8 = (uint32_t)(((int)c - WS) * 8);  // 8*(c-WS) mod 2^32
    const uint32_t limit = ((uint32_t)WS - c) << 3;     // keys with v < WS-c

    const uint32_t* eg = &ext8[g][0];
    int lo_ = 0, hi_ = 400;
    while (lo_ < hi_) {                    // 9 uniform steps
        int mid = (lo_ + hi_) >> 1;
        bool lt = eg[mid] < limit;
        lo_ = lt ? mid + 1 : lo_;
        hi_ = lt ? hi_ : mid;
    }
    uint32_t t_ = (uint32_t)lo_ << 2;      // byte offset into ext8[g]
    uint32_t K_ = eg[lo_];

    const char* eb = (const char*)&ext8[g][0];
    float* accG = acc + (g << 10) + d;     // + (tag<<7) per entry

    // ---- phase 4: region sweep, single 96KB bf16 tile ----
    for (int r = 0; r < NREG; ++r) {
        const int lo  = r * TSZ;
        const int len = (TSZ < WS - lo) ? TSZ : (WS - lo);   // last: 33920
        __syncthreads();                   // prev tile consumed (or ph 0-3)

        for (int s = tid; s < (len >> 3); s += NTHR)   // 16B = 8 entries
            GLOAD_LDS16(wbf + lo + (s << 3), &tile[s << 3]);
        __syncthreads();                   // vmcnt drained by barrier

        const uint32_t len8 = (uint32_t)len << 3;
        const uint32_t CL   = C8 - (((uint32_t)lo) << 3);
        const char* tb = (const char*)&tile[0];

        uint32_t u = K_ + CL;              // 8*(h-lo) + tag
        while (u < len8) {
            const uint32_t raw =
                *(const uint16_t*)(tb + ((u >> 2) & ~1u));   // ds_read_u16
            const float v = __uint_as_float(raw << 16);      // bf16 -> f32
            atomicAdd(accG + ((u & 7u) << 7), v);            // ds_add_f32
            t_ += 4u;
            K_  = *(const uint32_t*)(eb + t_);
            u   = K_ + CL;
        }
    }
    __syncthreads();                       // all adds done

    // ---- phase 5: coalesced output ----
    for (int p = tid; p < BAGS_PB * EMB_DIM; p += NTHR)
        out[(size_t)bagBase * EMB_DIM + p] = acc[p];
}

// ---- fallback (ws too small): R7's proven fp32 single-tile kernel ----
#define RSIZE_FB 32768
#define NREG_FB  62
#define EXT_N    104
#define SENT4    0x10000000u

__global__ __launch_bounds__(NTHR, 4) void heb_single(
    const float* __restrict__ weight,
    const int*   __restrict__ indices,
    float*       __restrict__ out)
{
    __shared__ __align__(16) float tile[RSIZE_FB];
    __shared__ uint32_t ext4[BAGS_PB][EXT_N];
    const int tid = threadIdx.x, d = tid & 127, bag_lo = tid >> 7;
    const int bagBase = blockIdx.x * BAGS_PB;
    uint32_t* araw = (uint32_t*)&tile[0];
    for (int p = tid; p < BAGS_PB * BAG_LEN; p += NTHR) {
        uint32_t g = (uint32_t)p / 50u, i = (uint32_t)p - g * 50u;
        uint64_t idx = (uint64_t)(uint32_t)indices[bagBase * BAG_LEN + p];
        araw[g * 52 + i] = (uint32_t)((idx * 9824516537ull) % (uint64_t)WS);
    }
    __syncthreads();
    for (int p = tid; p < BAGS_PB * BAG_LEN; p += NTHR) {
        uint32_t g = (uint32_t)p / 50u, i = (uint32_t)p - g * 50u;
        uint32_t v = araw[g * 52 + i];
        int rank = 0;
        for (int q = 0; q < BAG_LEN; ++q) {
            uint32_t w = araw[g * 52 + q];
            rank += (w < v || (w == v && q < (int)i)) ? 1 : 0;
        }
        ext4[g][rank] = v << 2;
        ext4[g][rank + 50] = (v + (uint32_t)WS) << 2;
    }
    for (int p = tid; p < BAGS_PB * 4; p += NTHR)
        ext4[p >> 2][100 + (p & 3)] = SENT4;
    __syncthreads();
    const uint32_t c = ((uint32_t)d * SBIG) % (uint32_t)WS;
    const uint32_t C4 = (uint32_t)(((int)c - WS) * 4);
    const uint32_t wmc4 = ((uint32_t)WS - c) << 2;
    uint32_t t4[8], h4[8]; float sm[8];
#pragma unroll
    for (int k = 0; k < 8; ++k) {
        const uint32_t* eg = &ext4[(bag_lo << 3) + k][0];
        int nlow = 0;
        for (int q = 0; q < BAG_LEN; ++q) nlow += (eg[q] < wmc4) ? 1 : 0;
        t4[k] = (uint32_t)nlow << 2; h4[k] = eg[nlow] + C4; sm[k] = 0.0f;
    }
    for (int r = 0; r < NREG_FB; ++r) {
        const int lo = r * RSIZE_FB;
        const int len = (RSIZE_FB < WS - lo) ? RSIZE_FB : (WS - lo);
        __syncthreads();
        for (int s = tid; s < (len >> 2); s += NTHR)
            GLOAD_LDS16(weight + lo + (s << 2), &tile[s << 2]);
        __syncthreads();
        const uint32_t lo4 = ((uint32_t)lo) << 2;
        const uint32_t hi4 = (r == NREG_FB - 1) ? (uint32_t)(4 * WS)
                                                : lo4 + ((uint32_t)RSIZE_FB << 2);
        const char* tb = (const char*)&tile[0];
#pragma unroll
        for (int k = 0; k < 8; ++k) {
            const char* eg = (const char*)&ext4[(bag_lo << 3) + k][0];
            uint32_t t_ = t4[k], h_ = h4[k]; float s_ = sm[k];
            while (h_ < hi4) {
                s_ += *(const float*)(tb + (h_ - lo4));
                t_ += 4u;
                h_ = *(const uint32_t*)(eg + t_) + C4;
            }
            t4[k] = t_; h4[k] = h_; sm[k] = s_;
        }
    }
#pragma unroll
    for (int k = 0; k < 8; ++k)
        out[(size_t)(bagBase + (bag_lo << 3) + k) * EMB_DIM + d] = sm[k];
}

extern "C" void kernel_launch(void* const* d_in, const int* in_sizes, int n_in,
                              void* d_out, int out_size, void* d_ws, size_t ws_size,
                              hipStream_t stream)
{
    const float* weight  = (const float*)d_in[0];   // [2,000,000] fp32
    const int*   indices = (const int*)d_in[1];     // [16384*50] int
    float*       out     = (float*)d_out;           // [16384*128] fp32

    if (ws_size >= (size_t)WS * sizeof(uint16_t)) {
        uint16_t* wbf = (uint16_t*)d_ws;
        conv_bf16<<<(WS / 8 + 1023) / 1024, 1024, 0, stream>>>(weight, wbf);
        heb_bf16v2<<<NBLK, NTHR, 0, stream>>>(wbf, indices, out);
    } else {
        heb_single<<<NBLK, NTHR, 0, stream>>>(weight, indices, out);
    }
}

// Round 12
// 704.870 us; speedup vs baseline: 1.0101x; 1.0101x over previous
//
#include <hip/hip_runtime.h>
#include <stdint.h>

// HashedEmbeddingBag: out[b][d] = sum_{i<50} weight[(idx[b][i]*P1 + d*P2) % WS]
// WS = 2,000,000; B = 16384; L = 50; D = 128.
//
// R11: R10's 8-bag merged stream + LDS ds_add accumulate, with the inner
// loop restructured into 4-entry batches to break R10's serialized chain
// (ext read -> branch -> tile read -> ds_add -> next ext read ~2 DS
// latencies/entry -> 660us at VALU 11%). Here: next-4 keys are loaded
// BEFORE the adds (pairable as ds_read2_b32), the loop branch depends only
// on the current block's u3 (keys monotone => u3 in-region implies all 4),
// so the K-load latency amortizes 4x and overlaps 4 tile reads + 4 adds.
// <=3-entry per-region tail uses the per-entry loop. Prologue (sort, 8-way
// rank-composition merge, rotation copies, sentinels) is R10-verbatim
// (correctness proven: absmax 0.25 across all replays).
// acc[bag][d] single-writer cells -> deterministic; bank d%32 exact 2-way.

#define WS       2000000
#define EMB_DIM  128
#define BAG_LEN  50
#define BATCH    16384

#define NBLK     256
#define NTHR     1024
#define BAGS_PB  64
#define TSZ      49152                   // bf16 tile entries (96KB)
#define NREG     41                      // 40 full + last 33,920
#define SBIG     300227u                 // P2 % WS
#define EXT8_N   808                     // 400 + 400 + 8 sentinels
#define SENT     0x7FFFFFFFu

#define GLOAD_LDS16(gp, lp)                                            \
    __builtin_amdgcn_global_load_lds(                                  \
        (const __attribute__((address_space(1))) uint32_t*)(gp),       \
        (__attribute__((address_space(3))) uint32_t*)(lp), 16, 0, 0)

__device__ __forceinline__ uint32_t f2bf(float x) {
    uint32_t u = __float_as_uint(x);
    return (u + 0x7FFFu + ((u >> 16) & 1u)) >> 16;   // RNE
}

// ---- pre-pass: fp32 table -> bf16 into d_ws ----
__global__ __launch_bounds__(1024) void conv_bf16(
    const float* __restrict__ w, uint16_t* __restrict__ o)
{
    const int i = (blockIdx.x * 1024 + threadIdx.x) * 8;
    if (i >= WS) return;
    const float4 f0 = *(const float4*)(w + i);
    const float4 f1 = *(const float4*)(w + i + 4);
    uint4 st;
    st.x = f2bf(f0.x) | (f2bf(f0.y) << 16);
    st.y = f2bf(f0.z) | (f2bf(f0.w) << 16);
    st.z = f2bf(f1.x) | (f2bf(f1.y) << 16);
    st.w = f2bf(f1.z) | (f2bf(f1.w) << 16);
    *(uint4*)(o + i) = st;               // i%8==0 -> 16B aligned
}

__global__ __launch_bounds__(NTHR, 4) void heb_bf16v3(
    const uint16_t* __restrict__ wbf,
    const int*      __restrict__ indices,
    float*          __restrict__ out)
{
    __shared__ __align__(16) uint16_t tile[TSZ];       // 96 KB
    __shared__ float    acc[BAGS_PB * EMB_DIM];        // 32 KB
    __shared__ uint32_t ext8[8][EXT8_N];               // 25.25 KB

    const int tid     = threadIdx.x;
    const int d       = tid & 127;
    const int g       = tid >> 7;          // group 0..7, owns bags 8g..8g+7
    const int bagBase = blockIdx.x * BAGS_PB;

    // sort scratch inside tile (dead before first staging)
    uint32_t* araw = (uint32_t*)&tile[0];          // words [0, 3328)
    uint32_t* S    = (uint32_t*)&tile[0] + 4096;   // words [4096, 7424)

    // ---- phase 0/1: zero acc; sentinel-fill ext; hash a = idx*P1 % WS ----
    for (int p = tid; p < BAGS_PB * EMB_DIM; p += NTHR) acc[p] = 0.0f;
    for (int p = tid; p < 8 * EXT8_N; p += NTHR)
        ((uint32_t*)ext8)[p] = SENT;
    for (int p = tid; p < BAGS_PB * BAG_LEN; p += NTHR) {
        uint32_t b = (uint32_t)p / 50u;
        uint32_t i = (uint32_t)p - b * 50u;
        uint64_t idx = (uint64_t)(uint32_t)indices[bagBase * BAG_LEN + p];
        araw[b * 52 + i] = (uint32_t)((idx * 9824516537ull) % (uint64_t)WS);
    }
    __syncthreads();

    // ---- phase 2a: rank-sort each bag (ties by index) -> S ----
    for (int p = tid; p < BAGS_PB * BAG_LEN; p += NTHR) {
        uint32_t b = (uint32_t)p / 50u;
        uint32_t i = (uint32_t)p - b * 50u;
        uint32_t v = araw[b * 52 + i];
        int rank = 0;
        for (int q = 0; q < BAG_LEN; ++q) {
            uint32_t w = araw[b * 52 + q];
            rank += (w < v || (w == v && q < (int)i)) ? 1 : 0;
        }
        S[b * 52 + rank] = v;
    }
    __syncthreads();

    // ---- phase 2b: 8-way merge per group via rank composition ----
    for (int p = tid; p < BAGS_PB * BAG_LEN; p += NTHR) {
        uint32_t bag = (uint32_t)p / 50u;
        uint32_t i   = (uint32_t)p - bag * 50u;
        uint32_t gg  = bag >> 3, b = bag & 7u;
        uint32_t v = S[bag * 52 + i];
        int r = (int)i;
        for (uint32_t b2 = 0; b2 < 8u; ++b2) {
            if (b2 == b) continue;
            const uint32_t* T = &S[((gg << 3) + b2) * 52];
            uint32_t key = (b2 < b) ? v + 1u : v;
            int lo = 0, hi = 50;
            while (lo < hi) {                  // 6 uniform steps
                int mid = (lo + hi) >> 1;
                bool lt = T[mid] < key;
                lo = lt ? mid + 1 : lo;
                hi = lt ? hi : mid;
            }
            r += lo;
        }
        ext8[gg][r]       = (v << 3) | b;                  // first copy
        ext8[gg][r + 400] = ((v + (uint32_t)WS) << 3) | b; // rotation copy
    }
    __syncthreads();                       // ext final; S/araw dead

    // ---- phase 3: per-thread stream init (one 400-entry stream) ----
    const uint32_t c  = ((uint32_t)d * SBIG) % (uint32_t)WS;
    const uint32_t C8 = (uint32_t)(((int)c - WS) * 8);  // 8*(c-WS) mod 2^32
    const uint32_t limit = ((uint32_t)WS - c) << 3;     // keys with v < WS-c

    const uint32_t* eg = &ext8[g][0];
    int lo_ = 0, hi_ = 400;
    while (lo_ < hi_) {                    // 9 uniform steps
        int mid = (lo_ + hi_) >> 1;
        bool lt = eg[mid] < limit;
        lo_ = lt ? mid + 1 : lo_;
        hi_ = lt ? hi_ : mid;
    }
    uint32_t t_ = (uint32_t)lo_;           // ENTRY index into ext8[g]

    const int accBase = (g << 10) + d;     // + (tag<<7) per entry

    // ---- phase 4: region sweep, single 96KB bf16 tile ----
    for (int r = 0; r < NREG; ++r) {
        const int lo  = r * TSZ;
        const int len = (TSZ < WS - lo) ? TSZ : (WS - lo);   // last: 33920
        __syncthreads();                   // prev tile consumed (or ph 0-3)

        for (int s = tid; s < (len >> 3); s += NTHR)   // 16B = 8 entries
            GLOAD_LDS16(wbf + lo + (s << 3), &tile[s << 3]);
        __syncthreads();                   // vmcnt drained by barrier

        const uint32_t len8 = (uint32_t)len << 3;
        const uint32_t CL   = C8 - (((uint32_t)lo) << 3);
        const char* tb = (const char*)&tile[0];

        // load current 4-key block (K monotone within the stream)
        uint32_t K0 = eg[t_],     K1 = eg[t_ + 1];
        uint32_t K2 = eg[t_ + 2], K3 = eg[t_ + 3];
        uint32_t u0 = K0 + CL, u3 = K3 + CL;

        // main: whole blocks of 4 (u3 in-region => all 4 in-region)
        while (u3 < len8) {
            // prefetch next block FIRST (pairs into ds_read2_b32; stays
            // in flight across the tile reads + adds below)
            const uint32_t n0 = eg[t_ + 4], n1 = eg[t_ + 5];
            const uint32_t n2 = eg[t_ + 6], n3 = eg[t_ + 7];
            const uint32_t u1 = K1 + CL, u2 = K2 + CL;
            // 4 independent tile reads
            const uint32_t r0 = *(const uint16_t*)(tb + ((u0 >> 2) & ~1u));
            const uint32_t r1 = *(const uint16_t*)(tb + ((u1 >> 2) & ~1u));
            const uint32_t r2 = *(const uint16_t*)(tb + ((u2 >> 2) & ~1u));
            const uint32_t r3 = *(const uint16_t*)(tb + ((u3 >> 2) & ~1u));
            atomicAdd(&acc[accBase + ((u0 & 7u) << 7)], __uint_as_float(r0 << 16));
            atomicAdd(&acc[accBase + ((u1 & 7u) << 7)], __uint_as_float(r1 << 16));
            atomicAdd(&acc[accBase + ((u2 & 7u) << 7)], __uint_as_float(r2 << 16));
            atomicAdd(&acc[accBase + ((u3 & 7u) << 7)], __uint_as_float(r3 << 16));
            t_ += 4u;
            K0 = n0; K1 = n1; K2 = n2; K3 = n3;
            u0 = K0 + CL; u3 = K3 + CL;
        }

        // tail: remaining <=3 in-region entries, one at a time
        while (u0 < len8) {
            const uint32_t raw = *(const uint16_t*)(tb + ((u0 >> 2) & ~1u));
            atomicAdd(&acc[accBase + ((u0 & 7u) << 7)], __uint_as_float(raw << 16));
            t_ += 1u;
            u0 = eg[t_] + CL;
        }
    }
    __syncthreads();                       // all adds done

    // ---- phase 5: coalesced output ----
    for (int p = tid; p < BAGS_PB * EMB_DIM; p += NTHR)
        out[(size_t)bagBase * EMB_DIM + p] = acc[p];
}

// ---- fallback (ws too small): R7's proven fp32 single-tile kernel ----
#define RSIZE_FB 32768
#define NREG_FB  62
#define EXT_N    104
#define SENT4    0x10000000u

__global__ __launch_bounds__(NTHR, 4) void heb_single(
    const float* __restrict__ weight,
    const int*   __restrict__ indices,
    float*       __restrict__ out)
{
    __shared__ __align__(16) float tile[RSIZE_FB];
    __shared__ uint32_t ext4[BAGS_PB][EXT_N];
    const int tid = threadIdx.x, d = tid & 127, bag_lo = tid >> 7;
    const int bagBase = blockIdx.x * BAGS_PB;
    uint32_t* araw = (uint32_t*)&tile[0];
    for (int p = tid; p < BAGS_PB * BAG_LEN; p += NTHR) {
        uint32_t g = (uint32_t)p / 50u, i = (uint32_t)p - g * 50u;
        uint64_t idx = (uint64_t)(uint32_t)indices[bagBase * BAG_LEN + p];
        araw[g * 52 + i] = (uint32_t)((idx * 9824516537ull) % (uint64_t)WS);
    }
    __syncthreads();
    for (int p = tid; p < BAGS_PB * BAG_LEN; p += NTHR) {
        uint32_t g = (uint32_t)p / 50u, i = (uint32_t)p - g * 50u;
        uint32_t v = araw[g * 52 + i];
        int rank = 0;
        for (int q = 0; q < BAG_LEN; ++q) {
            uint32_t w = araw[g * 52 + q];
            rank += (w < v || (w == v && q < (int)i)) ? 1 : 0;
        }
        ext4[g][rank] = v << 2;
        ext4[g][rank + 50] = (v + (uint32_t)WS) << 2;
    }
    for (int p = tid; p < BAGS_PB * 4; p += NTHR)
        ext4[p >> 2][100 + (p & 3)] = SENT4;
    __syncthreads();
    const uint32_t c = ((uint32_t)d * SBIG) % (uint32_t)WS;
    const uint32_t C4 = (uint32_t)(((int)c - WS) * 4);
    const uint32_t wmc4 = ((uint32_t)WS - c) << 2;
    uint32_t t4[8], h4[8]; float sm[8];
#pragma unroll
    for (int k = 0; k < 8; ++k) {
        const uint32_t* eg = &ext4[(bag_lo << 3) + k][0];
        int nlow = 0;
        for (int q = 0; q < BAG_LEN; ++q) nlow += (eg[q] < wmc4) ? 1 : 0;
        t4[k] = (uint32_t)nlow << 2; h4[k] = eg[nlow] + C4; sm[k] = 0.0f;
    }
    for (int r = 0; r < NREG_FB; ++r) {
        const int lo = r * RSIZE_FB;
        const int len = (RSIZE_FB < WS - lo) ? RSIZE_FB : (WS - lo);
        __syncthreads();
        for (int s = tid; s < (len >> 2); s += NTHR)
            GLOAD_LDS16(weight + lo + (s << 2), &tile[s << 2]);
        __syncthreads();
        const uint32_t lo4 = ((uint32_t)lo) << 2;
        const uint32_t hi4 = (r == NREG_FB - 1) ? (uint32_t)(4 * WS)
                                                : lo4 + ((uint32_t)RSIZE_FB << 2);
        const char* tb = (const char*)&tile[0];
#pragma unroll
        for (int k = 0; k < 8; ++k) {
            const char* eg = (const char*)&ext4[(bag_lo << 3) + k][0];
            uint32_t t_ = t4[k], h_ = h4[k]; float s_ = sm[k];
            while (h_ < hi4) {
                s_ += *(const float*)(tb + (h_ - lo4));
                t_ += 4u;
                h_ = *(const uint32_t*)(eg + t_) + C4;
            }
            t4[k] = t_; h4[k] = h_; sm[k] = s_;
        }
    }
#pragma unroll
    for (int k = 0; k < 8; ++k)
        out[(size_t)(bagBase + (bag_lo << 3) + k) * EMB_DIM + d] = sm[k];
}

extern "C" void kernel_launch(void* const* d_in, const int* in_sizes, int n_in,
                              void* d_out, int out_size, void* d_ws, size_t ws_size,
                              hipStream_t stream)
{
    const float* weight  = (const float*)d_in[0];   // [2,000,000] fp32
    const int*   indices = (const int*)d_in[1];     // [16384*50] int
    float*       out     = (float*)d_out;           // [16384*128] fp32

    if (ws_size >= (size_t)WS * sizeof(uint16_t)) {
        uint16_t* wbf = (uint16_t*)d_ws;
        conv_bf16<<<(WS / 8 + 1023) / 1024, 1024, 0, stream>>>(weight, wbf);
        heb_bf16v3<<<NBLK, NTHR, 0, stream>>>(wbf, indices, out);
    } else {
        heb_single<<<NBLK, NTHR, 0, stream>>>(weight, indices, out);
    }
}

// Round 13
// 338.929 us; speedup vs baseline: 2.1006x; 2.0797x over previous
//
#include <hip/hip_runtime.h>
#include <hip/hip_cooperative_groups.h>
#include <stdint.h>

namespace cg = cooperative_groups;

// HashedEmbeddingBag: out[b][d] = sum_{i<50} weight[(idx[b][i]*P1 + d*P2) % WS]
// WS = 2,000,000; B = 16384; L = 50; D = 128.
//
// R12: cooperative fusion of R9 (the proven 176us sweep; 227us total with
// separate conv kernel). LESSON (R2/R3/R10/R11): gfx950 LDS ds_add_f32 is
// ~130 cyc/op throughput-serialized -> never in a hot loop; register
// accumulate only. Structure: each block converts one 8192-entry slice of
// the fp32 table to bf16 in d_ws (1 uint4/thread), runs the R9 prologue
// (per-bag rank sort + 4-way rank-composition merge -> 2 quad-streams per
// thread), grid.sync() (device-scope fence: wbf visible cross-XCD), then
// R9's sweep verbatim: 31 regions x 128KB bf16 tile via global_load_lds
// 16B; per entry: ds_read_u16 tile + ds_read key, 4-way select into
// register sums. bf16 quantization absmax 0.25 << 0.71 threshold (R9/R10
// measured). Fallback (ws < 4MB): R7's fp32 single-tile kernel.

#define WS       2000000
#define EMB_DIM  128
#define BAG_LEN  50
#define BATCH    16384

#define NBLK     256
#define NTHR     1024
#define BAGS_PB  64
#define NQUAD    16                      // 4-bag quads per block
#define QEXT     408                     // 200 + 200 + 8 sentinels
#define RSZE     65536                   // tile entries (bf16) = 128KB
#define NREG     31                      // 30 full + last 33,920
#define SBIG     300227u                 // P2 % WS
#define SENT     0x10000000u             // sentinel key; u stays >= len4

#define GLOAD_LDS16(gp, lp)                                            \
    __builtin_amdgcn_global_load_lds(                                  \
        (const __attribute__((address_space(1))) uint32_t*)(gp),       \
        (__attribute__((address_space(3))) uint32_t*)(lp), 16, 0, 0)

__device__ __forceinline__ uint32_t f2bf(float x) {
    uint32_t u = __float_as_uint(x);
    return (u + 0x7FFFu + ((u >> 16) & 1u)) >> 16;   // RNE
}

__global__ __launch_bounds__(NTHR, 4) void heb_coop(
    const float* __restrict__ weight,
    const int*   __restrict__ indices,
    float*       __restrict__ out,
    uint16_t*                 wbf)
{
    __shared__ __align__(16) uint16_t tile[RSZE];      // 128 KB
    __shared__ uint32_t extq[NQUAD][QEXT];             // 25.5 KB

    const int tid     = threadIdx.x;
    const int d       = tid & 127;
    const int g       = tid >> 7;          // group 0..7 (owns bags 8g..8g+7)
    const int bagBase = blockIdx.x * BAGS_PB;

    // ---- phase A: convert my 8192-entry slice of the table to bf16 ----
    {
        const int idx = blockIdx.x * 8192 + tid * 8;   // WS % 8 == 0
        if (idx < WS) {
            const float4 f0 = *(const float4*)(weight + idx);
            const float4 f1 = *(const float4*)(weight + idx + 4);
            uint4 st;
            st.x = f2bf(f0.x) | (f2bf(f0.y) << 16);
            st.y = f2bf(f0.z) | (f2bf(f0.w) << 16);
            st.z = f2bf(f1.x) | (f2bf(f1.y) << 16);
            st.w = f2bf(f1.z) | (f2bf(f1.w) << 16);
            *(uint4*)(wbf + idx) = st;                 // 16B aligned
        }
    }

    // sort scratch in tile (dead before first staging): two [64][52] arrays
    uint32_t* araw = (uint32_t*)&tile[0];          // words [0, 3328)
    uint32_t* S    = (uint32_t*)&tile[0] + 4096;   // words [4096, 7424)

    // ---- phase 1: sentinel-fill ext; load indices; a = idx*P1 % WS ----
    for (int p = tid; p < NQUAD * QEXT; p += NTHR)
        ((uint32_t*)extq)[p] = SENT;               // deterministic fill
    for (int p = tid; p < BAGS_PB * BAG_LEN; p += NTHR) {
        uint32_t b = (uint32_t)p / 50u;
        uint32_t i = (uint32_t)p - b * 50u;
        uint64_t idx = (uint64_t)(uint32_t)indices[bagBase * BAG_LEN + p];
        araw[b * 52 + i] = (uint32_t)((idx * 9824516537ull) % (uint64_t)WS);
    }
    __syncthreads();

    // ---- phase 2a: rank-sort each bag (ties by index) -> S ----
    for (int p = tid; p < BAGS_PB * BAG_LEN; p += NTHR) {
        uint32_t b = (uint32_t)p / 50u;
        uint32_t i = (uint32_t)p - b * 50u;
        uint32_t v = araw[b * 52 + i];
        int rank = 0;
        for (int q = 0; q < BAG_LEN; ++q) {
            uint32_t w = araw[b * 52 + q];
            rank += (w < v || (w == v && q < (int)i)) ? 1 : 0;
        }
        S[b * 52 + rank] = v;
    }
    __syncthreads();

    // ---- phase 2b: 4-way merge per quad via rank composition ----
    for (int p = tid; p < BAGS_PB * BAG_LEN; p += NTHR) {
        uint32_t bag = (uint32_t)p / 50u;
        uint32_t i   = (uint32_t)p - bag * 50u;
        uint32_t qd  = bag >> 2, b = bag & 3u;
        uint32_t v = S[bag * 52 + i];
        int r = (int)i;
        for (uint32_t b2 = 0; b2 < 4u; ++b2) {
            if (b2 == b) continue;
            const uint32_t* T = &S[((qd << 2) + b2) * 52];
            uint32_t key = (b2 < b) ? v + 1u : v;  // tie-break by bag id
            int lo = 0, hi = 50;
            while (lo < hi) {                      // ~6 uniform steps
                int mid = (lo + hi) >> 1;
                bool lt = T[mid] < key;
                lo = lt ? mid + 1 : lo;
                hi = lt ? hi : mid;
            }
            r += lo;
        }
        extq[qd][r]       = (v << 2) | b;                  // first copy
        extq[qd][r + 200] = ((v + (uint32_t)WS) << 2) | b; // rotation copy
    }
    __syncthreads();                       // ext final; S/araw dead

    // ---- phase 3: per-thread stream init (2 quads per thread) ----
    const uint32_t c  = ((uint32_t)d * SBIG) % (uint32_t)WS;
    const uint32_t C4 = (uint32_t)(((int)c - WS) * 4);  // 4*(c-WS) mod 2^32
    const uint32_t limit = ((uint32_t)WS - c) << 2;     // keys with v < WS-c

    uint32_t t4[2], K[2];
    float sm[2][4];
#pragma unroll
    for (int qi = 0; qi < 2; ++qi) {
        const uint32_t* eg = &extq[(g << 1) + qi][0];
        int lo = 0, hi = 200;
        while (lo < hi) {
            int mid = (lo + hi) >> 1;
            bool lt = eg[mid] < limit;
            lo = lt ? mid + 1 : lo;
            hi = lt ? hi : mid;
        }
        t4[qi] = (uint32_t)lo << 2;        // byte offset into extq row
        K[qi]  = eg[lo];
        sm[qi][0] = sm[qi][1] = sm[qi][2] = sm[qi][3] = 0.0f;
    }

    // ---- grid-wide sync: all conv slices written & visible ----
    __threadfence();                       // device-scope release
    cg::this_grid().sync();

    // ---- phase 4: region sweep, single 128KB bf16 tile (R9-verbatim) ----
    for (int r = 0; r < NREG; ++r) {
        const int lo  = r * RSZE;
        const int len = (RSZE < WS - lo) ? RSZE : (WS - lo);  // last: 33920
        __syncthreads();                   // prev tile consumed

        // stage bf16 region: 16B per lane = 8 entries, contiguous
        for (int s = tid; s < (len >> 3); s += NTHR)
            GLOAD_LDS16(wbf + lo + (s << 3), &tile[s << 3]);
        __syncthreads();                   // barrier drains vmcnt

        const uint32_t len4 = (uint32_t)len << 2;
        const uint32_t CL   = C4 - (((uint32_t)lo) << 2);
        const char* tb = (const char*)&tile[0];

#pragma unroll
        for (int qi = 0; qi < 2; ++qi) {
            const char* eg = (const char*)&extq[(g << 1) + qi][0];
            uint32_t t_ = t4[qi], K_ = K[qi];
            uint32_t u  = K_ + CL;         // 4*(h-lo) + tag
            float s0 = sm[qi][0], s1 = sm[qi][1];
            float s2 = sm[qi][2], s3 = sm[qi][3];
            while (u < len4) {
                const uint32_t raw =
                    *(const uint16_t*)(tb + ((u >> 1) & ~1u)); // ds_read_u16
                const float v = __uint_as_float(raw << 16);    // bf16 -> f32
                const uint32_t tag = u & 3u;
                s0 += (tag == 0u) ? v : 0.0f;
                s1 += (tag == 1u) ? v : 0.0f;
                s2 += (tag == 2u) ? v : 0.0f;
                s3 += (tag == 3u) ? v : 0.0f;
                t_ += 4u;
                K_  = *(const uint32_t*)(eg + t_);
                u   = K_ + CL;
            }
            t4[qi] = t_; K[qi] = K_;
            sm[qi][0] = s0; sm[qi][1] = s1; sm[qi][2] = s2; sm[qi][3] = s3;
        }
    }

    // ---- phase 5: coalesced output (bag = 8g + 4qi + tag) ----
#pragma unroll
    for (int qi = 0; qi < 2; ++qi)
#pragma unroll
        for (int b = 0; b < 4; ++b) {
            const int bag = (g << 3) + (qi << 2) + b;
            out[(size_t)(bagBase + bag) * EMB_DIM + d] = sm[qi][b];
        }
}

// ---- fallback (ws too small): R7's proven fp32 single-tile kernel ----
#define RSIZE_FB 32768
#define NREG_FB  62
#define EXT_N    104
#define SENT4    0x10000000u

__global__ __launch_bounds__(NTHR, 4) void heb_single(
    const float* __restrict__ weight,
    const int*   __restrict__ indices,
    float*       __restrict__ out)
{
    __shared__ __align__(16) float tile[RSIZE_FB];
    __shared__ uint32_t ext4[BAGS_PB][EXT_N];
    const int tid = threadIdx.x, d = tid & 127, bag_lo = tid >> 7;
    const int bagBase = blockIdx.x * BAGS_PB;
    uint32_t* araw = (uint32_t*)&tile[0];
    for (int p = tid; p < BAGS_PB * BAG_LEN; p += NTHR) {
        uint32_t g = (uint32_t)p / 50u, i = (uint32_t)p - g * 50u;
        uint64_t idx = (uint64_t)(uint32_t)indices[bagBase * BAG_LEN + p];
        araw[g * 52 + i] = (uint32_t)((idx * 9824516537ull) % (uint64_t)WS);
    }
    __syncthreads();
    for (int p = tid; p < BAGS_PB * BAG_LEN; p += NTHR) {
        uint32_t g = (uint32_t)p / 50u, i = (uint32_t)p - g * 50u;
        uint32_t v = araw[g * 52 + i];
        int rank = 0;
        for (int q = 0; q < BAG_LEN; ++q) {
            uint32_t w = araw[g * 52 + q];
            rank += (w < v || (w == v && q < (int)i)) ? 1 : 0;
        }
        ext4[g][rank] = v << 2;
        ext4[g][rank + 50] = (v + (uint32_t)WS) << 2;
    }
    for (int p = tid; p < BAGS_PB * 4; p += NTHR)
        ext4[p >> 2][100 + (p & 3)] = SENT4;
    __syncthreads();
    const uint32_t c = ((uint32_t)d * SBIG) % (uint32_t)WS;
    const uint32_t C4 = (uint32_t)(((int)c - WS) * 4);
    const uint32_t wmc4 = ((uint32_t)WS - c) << 2;
    uint32_t t4[8], h4[8]; float sm[8];
#pragma unroll
    for (int k = 0; k < 8; ++k) {
        const uint32_t* eg = &ext4[(bag_lo << 3) + k][0];
        int nlow = 0;
        for (int q = 0; q < BAG_LEN; ++q) nlow += (eg[q] < wmc4) ? 1 : 0;
        t4[k] = (uint32_t)nlow << 2; h4[k] = eg[nlow] + C4; sm[k] = 0.0f;
    }
    for (int r = 0; r < NREG_FB; ++r) {
        const int lo = r * RSIZE_FB;
        const int len = (RSIZE_FB < WS - lo) ? RSIZE_FB : (WS - lo);
        __syncthreads();
        for (int s = tid; s < (len >> 2); s += NTHR)
            GLOAD_LDS16(weight + lo + (s << 2), &tile[s << 2]);
        __syncthreads();
        const uint32_t lo4 = ((uint32_t)lo) << 2;
        const uint32_t hi4 = (r == NREG_FB - 1) ? (uint32_t)(4 * WS)
                                                : lo4 + ((uint32_t)RSIZE_FB << 2);
        const char* tb = (const char*)&tile[0];
#pragma unroll
        for (int k = 0; k < 8; ++k) {
            const char* eg = (const char*)&ext4[(bag_lo << 3) + k][0];
            uint32_t t_ = t4[k], h_ = h4[k]; float s_ = sm[k];
            while (h_ < hi4) {
                s_ += *(const float*)(tb + (h_ - lo4));
                t_ += 4u;
                h_ = *(const uint32_t*)(eg + t_) + C4;
            }
            t4[k] = t_; h4[k] = h_; sm[k] = s_;
        }
    }
#pragma unroll
    for (int k = 0; k < 8; ++k)
        out[(size_t)(bagBase + (bag_lo << 3) + k) * EMB_DIM + d] = sm[k];
}

extern "C" void kernel_launch(void* const* d_in, const int* in_sizes, int n_in,
                              void* d_out, int out_size, void* d_ws, size_t ws_size,
                              hipStream_t stream)
{
    const float* weight  = (const float*)d_in[0];   // [2,000,000] fp32
    const int*   indices = (const int*)d_in[1];     // [16384*50] int
    float*       out     = (float*)d_out;           // [16384*128] fp32

    if (ws_size >= (size_t)WS * sizeof(uint16_t)) {
        uint16_t* wbf = (uint16_t*)d_ws;
        void* args[] = {(void*)&weight, (void*)&indices, (void*)&out, (void*)&wbf};
        hipLaunchCooperativeKernel((const void*)heb_coop,
                                   dim3(NBLK), dim3(NTHR), args, 0, stream);
    } else {
        heb_single<<<NBLK, NTHR, 0, stream>>>(weight, indices, out);
    }
}

// Round 14
// 270.562 us; speedup vs baseline: 2.6314x; 1.2527x over previous
//
#include <hip/hip_runtime.h>
#include <stdint.h>

// HashedEmbeddingBag: out[b][d] = sum_{i<50} weight[(idx[b][i]*P1 + d*P2) % WS]
// WS = 2,000,000; B = 16384; L = 50; D = 128.
//
// R13: single plain kernel; fp32->bf16 conversion fused into staging.
// Launch-overhead facts (measured): plain 1-kernel ~2us (R7), 2-kernel
// graph ~47us node gap (R9), cooperative ~68us + slower sweep (R12).
// LDS-atomic fact (R10/R11): ds_add_f32 ~130cyc serialized - never in hot
// loops; register accumulate only. So: R9's proven prologue + sweep loop
// verbatim (2 quad-merged sorted streams/thread, 4-way select into
// register sums, 31 regions x 128KB bf16 tile), but the tile is staged by
// reading the fp32 table directly (2x global_load_dwordx4 per 8 entries),
// converting in-register (round-half-up (u+0x8000)>>16; differs from RNE
// only on exact ties, absmax stays ~0.25), packing pairs with v_perm_b32,
// and ds_write_b128. No d_ws, no second kernel, no grid sync.

#define WS       2000000
#define EMB_DIM  128
#define BAG_LEN  50
#define BATCH    16384

#define NBLK     256
#define NTHR     1024
#define BAGS_PB  64
#define NQUAD    16                      // 4-bag quads per block
#define QEXT     408                     // 200 + 200 + 8 sentinels
#define RSZE     65536                   // tile entries (bf16) = 128KB
#define NREG     31                      // 30 full + last 33,920
#define SBIG     300227u                 // P2 % WS
#define SENT     0x10000000u             // sentinel key; u stays >= len4

__global__ __launch_bounds__(NTHR, 4) void heb_fused(
    const float* __restrict__ weight,
    const int*   __restrict__ indices,
    float*       __restrict__ out)
{
    __shared__ __align__(16) uint16_t tile[RSZE];      // 128 KB
    __shared__ uint32_t extq[NQUAD][QEXT];             // 25.5 KB

    const int tid     = threadIdx.x;
    const int d       = tid & 127;
    const int g       = tid >> 7;          // group 0..7 (owns bags 8g..8g+7)
    const int bagBase = blockIdx.x * BAGS_PB;

    // sort scratch in tile (dead before first staging): two [64][52] arrays
    uint32_t* araw = (uint32_t*)&tile[0];          // words [0, 3328)
    uint32_t* S    = (uint32_t*)&tile[0] + 4096;   // words [4096, 7424)

    // ---- phase 1: sentinel-fill ext; load indices; a = idx*P1 % WS ----
    for (int p = tid; p < NQUAD * QEXT; p += NTHR)
        ((uint32_t*)extq)[p] = SENT;               // deterministic fill
    for (int p = tid; p < BAGS_PB * BAG_LEN; p += NTHR) {
        uint32_t b = (uint32_t)p / 50u;
        uint32_t i = (uint32_t)p - b * 50u;
        uint64_t idx = (uint64_t)(uint32_t)indices[bagBase * BAG_LEN + p];
        araw[b * 52 + i] = (uint32_t)((idx * 9824516537ull) % (uint64_t)WS);
    }
    __syncthreads();

    // ---- phase 2a: rank-sort each bag (ties by index) -> S ----
    for (int p = tid; p < BAGS_PB * BAG_LEN; p += NTHR) {
        uint32_t b = (uint32_t)p / 50u;
        uint32_t i = (uint32_t)p - b * 50u;
        uint32_t v = araw[b * 52 + i];
        int rank = 0;
        for (int q = 0; q < BAG_LEN; ++q) {
            uint32_t w = araw[b * 52 + q];
            rank += (w < v || (w == v && q < (int)i)) ? 1 : 0;
        }
        S[b * 52 + rank] = v;
    }
    __syncthreads();

    // ---- phase 2b: 4-way merge per quad via rank composition ----
    for (int p = tid; p < BAGS_PB * BAG_LEN; p += NTHR) {
        uint32_t bag = (uint32_t)p / 50u;
        uint32_t i   = (uint32_t)p - bag * 50u;
        uint32_t qd  = bag >> 2, b = bag & 3u;
        uint32_t v = S[bag * 52 + i];
        int r = (int)i;
        for (uint32_t b2 = 0; b2 < 4u; ++b2) {
            if (b2 == b) continue;
            const uint32_t* T = &S[((qd << 2) + b2) * 52];
            uint32_t key = (b2 < b) ? v + 1u : v;  // tie-break by bag id
            int lo = 0, hi = 50;
            while (lo < hi) {                      // ~6 uniform steps
                int mid = (lo + hi) >> 1;
                bool lt = T[mid] < key;
                lo = lt ? mid + 1 : lo;
                hi = lt ? hi : mid;
            }
            r += lo;
        }
        extq[qd][r]       = (v << 2) | b;                  // first copy
        extq[qd][r + 200] = ((v + (uint32_t)WS) << 2) | b; // rotation copy
    }
    __syncthreads();                       // ext final; S/araw dead

    // ---- phase 3: per-thread stream init (2 quads per thread) ----
    const uint32_t c  = ((uint32_t)d * SBIG) % (uint32_t)WS;
    const uint32_t C4 = (uint32_t)(((int)c - WS) * 4);  // 4*(c-WS) mod 2^32
    const uint32_t limit = ((uint32_t)WS - c) << 2;     // keys with v < WS-c

    uint32_t t4[2], K[2];
    float sm[2][4];
#pragma unroll
    for (int qi = 0; qi < 2; ++qi) {
        const uint32_t* eg = &extq[(g << 1) + qi][0];
        int lo = 0, hi = 200;
        while (lo < hi) {
            int mid = (lo + hi) >> 1;
            bool lt = eg[mid] < limit;
            lo = lt ? mid + 1 : lo;
            hi = lt ? hi : mid;
        }
        t4[qi] = (uint32_t)lo << 2;        // byte offset into extq row
        K[qi]  = eg[lo];
        sm[qi][0] = sm[qi][1] = sm[qi][2] = sm[qi][3] = 0.0f;
    }

    // ---- phase 4: region sweep; fused fp32->bf16 staging ----
    for (int r = 0; r < NREG; ++r) {
        const int lo  = r * RSZE;
        const int len = (RSZE < WS - lo) ? RSZE : (WS - lo);  // last: 33920
        __syncthreads();                   // prev tile consumed (or ph 1-3)

        // stage: 8 fp32 -> 8 bf16 (round-half-up) -> one ds_write_b128
        for (int s8 = tid; s8 < (len >> 3); s8 += NTHR) {
            const float4 f0 = *(const float4*)(weight + lo + (s8 << 3));
            const float4 f1 = *(const float4*)(weight + lo + (s8 << 3) + 4);
            const uint32_t a0 = __float_as_uint(f0.x) + 0x8000u;
            const uint32_t a1 = __float_as_uint(f0.y) + 0x8000u;
            const uint32_t a2 = __float_as_uint(f0.z) + 0x8000u;
            const uint32_t a3 = __float_as_uint(f0.w) + 0x8000u;
            const uint32_t a4 = __float_as_uint(f1.x) + 0x8000u;
            const uint32_t a5 = __float_as_uint(f1.y) + 0x8000u;
            const uint32_t a6 = __float_as_uint(f1.z) + 0x8000u;
            const uint32_t a7 = __float_as_uint(f1.w) + 0x8000u;
            uint4 st;                      // {hi16(odd), hi16(even)} pairs
            st.x = __builtin_amdgcn_perm(a1, a0, 0x07060302u);
            st.y = __builtin_amdgcn_perm(a3, a2, 0x07060302u);
            st.z = __builtin_amdgcn_perm(a5, a4, 0x07060302u);
            st.w = __builtin_amdgcn_perm(a7, a6, 0x07060302u);
            *(uint4*)&tile[s8 << 3] = st;  // 16B-aligned ds_write_b128
        }
        __syncthreads();                   // tile valid

        const uint32_t len4 = (uint32_t)len << 2;
        const uint32_t CL   = C4 - (((uint32_t)lo) << 2);
        const char* tb = (const char*)&tile[0];

#pragma unroll
        for (int qi = 0; qi < 2; ++qi) {
            const char* eg = (const char*)&extq[(g << 1) + qi][0];
            uint32_t t_ = t4[qi], K_ = K[qi];
            uint32_t u  = K_ + CL;         // 4*(h-lo) + tag
            float s0 = sm[qi][0], s1 = sm[qi][1];
            float s2 = sm[qi][2], s3 = sm[qi][3];
            while (u < len4) {
                const uint32_t raw =
                    *(const uint16_t*)(tb + ((u >> 1) & ~1u)); // ds_read_u16
                const float v = __uint_as_float(raw << 16);    // bf16 -> f32
                const uint32_t tag = u & 3u;
                s0 += (tag == 0u) ? v : 0.0f;
                s1 += (tag == 1u) ? v : 0.0f;
                s2 += (tag == 2u) ? v : 0.0f;
                s3 += (tag == 3u) ? v : 0.0f;
                t_ += 4u;
                K_  = *(const uint32_t*)(eg + t_);
                u   = K_ + CL;
            }
            t4[qi] = t_; K[qi] = K_;
            sm[qi][0] = s0; sm[qi][1] = s1; sm[qi][2] = s2; sm[qi][3] = s3;
        }
    }

    // ---- phase 5: coalesced output (bag = 8g + 4qi + tag) ----
#pragma unroll
    for (int qi = 0; qi < 2; ++qi)
#pragma unroll
        for (int b = 0; b < 4; ++b) {
            const int bag = (g << 3) + (qi << 2) + b;
            out[(size_t)(bagBase + bag) * EMB_DIM + d] = sm[qi][b];
        }
}

extern "C" void kernel_launch(void* const* d_in, const int* in_sizes, int n_in,
                              void* d_out, int out_size, void* d_ws, size_t ws_size,
                              hipStream_t stream)
{
    const float* weight  = (const float*)d_in[0];   // [2,000,000] fp32
    const int*   indices = (const int*)d_in[1];     // [16384*50] int
    float*       out     = (float*)d_out;           // [16384*128] fp32

    heb_fused<<<NBLK, NTHR, 0, stream>>>(weight, indices, out);
}

// Round 15
// 230.920 us; speedup vs baseline: 3.0831x; 1.1717x over previous
//
#include <hip/hip_runtime.h>
#include <stdint.h>

// HashedEmbeddingBag: out[b][d] = sum_{i<50} weight[(idx[b][i]*P1 + d*P2) % WS]
// WS = 2,000,000; B = 16384; L = 50; D = 128.
//
// R14: R9's champion two-kernel structure (conv fp32->bf16 into d_ws, then
// 31-region 128KB-bf16-tile sweep with 2 quad-merged sorted streams/thread
// and register select-accumulate) + 4-entry straight-line batches in the
// gather loop. Facts bank: LDS ds_add_f32 ~130cyc serialized (R10/R11 -
// never in hot loops); fused fp32 staging costs +77us vs async bf16
// global_load_lds (R13); coop launch +68us (R12); two-kernel gap ~46us
// (R9) - accepted. Batching invariant: keys monotone + regions ascending
// => entry t is first unprocessed with h >= lo, so u3 < len4 implies
// u0..u3 all in [0,len4): process 4 with NO per-entry branch; keys read
// as ds_read_b128; next-K load issued before the selects. Tail <=3 via
// the single-step loop. t <= 400, reads reach eg[403] < 408 sentinels.

#define WS       2000000
#define EMB_DIM  128
#define BAG_LEN  50
#define BATCH    16384

#define NBLK     256
#define NTHR     1024
#define BAGS_PB  64
#define NQUAD    16                      // 4-bag quads per block
#define QEXT     408                     // 200 + 200 + 8 sentinels
#define RSZE     65536                   // tile entries (bf16) = 128KB
#define NREG     31                      // 30 full + last 33,920
#define SBIG     300227u                 // P2 % WS
#define SENT     0x10000000u             // sentinel key; u stays >= len4

#define GLOAD_LDS16(gp, lp)                                            \
    __builtin_amdgcn_global_load_lds(                                  \
        (const __attribute__((address_space(1))) uint32_t*)(gp),       \
        (__attribute__((address_space(3))) uint32_t*)(lp), 16, 0, 0)

__device__ __forceinline__ uint32_t f2bf(float x) {
    uint32_t u = __float_as_uint(x);
    return (u + 0x7FFFu + ((u >> 16) & 1u)) >> 16;   // RNE
}

// ---- pre-pass: fp32 table -> bf16 into d_ws ----
__global__ __launch_bounds__(256) void conv_bf16(
    const float* __restrict__ w, uint16_t* __restrict__ o)
{
    const int i = (blockIdx.x * 256 + threadIdx.x) * 8;
    if (i >= WS) return;
    const float4 f0 = *(const float4*)(w + i);
    const float4 f1 = *(const float4*)(w + i + 4);
    uint4 st;
    st.x = f2bf(f0.x) | (f2bf(f0.y) << 16);
    st.y = f2bf(f0.z) | (f2bf(f0.w) << 16);
    st.z = f2bf(f1.x) | (f2bf(f1.y) << 16);
    st.w = f2bf(f1.z) | (f2bf(f1.w) << 16);
    *(uint4*)(o + i) = st;               // i%8==0 -> 16B aligned
}

__global__ __launch_bounds__(NTHR, 4) void heb_bf16b(
    const uint16_t* __restrict__ wbf,
    const int*      __restrict__ indices,
    float*          __restrict__ out)
{
    __shared__ __align__(16) uint16_t tile[RSZE];      // 128 KB
    __shared__ uint32_t extq[NQUAD][QEXT];             // 25.5 KB

    const int tid     = threadIdx.x;
    const int d       = tid & 127;
    const int g       = tid >> 7;          // group 0..7 (owns bags 8g..8g+7)
    const int bagBase = blockIdx.x * BAGS_PB;

    // sort scratch in tile (dead before first staging): two [64][52] arrays
    uint32_t* araw = (uint32_t*)&tile[0];          // words [0, 3328)
    uint32_t* S    = (uint32_t*)&tile[0] + 4096;   // words [4096, 7424)

    // ---- phase 1: sentinel-fill ext; load indices; a = idx*P1 % WS ----
    for (int p = tid; p < NQUAD * QEXT; p += NTHR)
        ((uint32_t*)extq)[p] = SENT;               // deterministic fill
    for (int p = tid; p < BAGS_PB * BAG_LEN; p += NTHR) {
        uint32_t b = (uint32_t)p / 50u;
        uint32_t i = (uint32_t)p - b * 50u;
        uint64_t idx = (uint64_t)(uint32_t)indices[bagBase * BAG_LEN + p];
        araw[b * 52 + i] = (uint32_t)((idx * 9824516537ull) % (uint64_t)WS);
    }
    __syncthreads();

    // ---- phase 2a: rank-sort each bag (ties by index) -> S ----
    for (int p = tid; p < BAGS_PB * BAG_LEN; p += NTHR) {
        uint32_t b = (uint32_t)p / 50u;
        uint32_t i = (uint32_t)p - b * 50u;
        uint32_t v = araw[b * 52 + i];
        int rank = 0;
        for (int q = 0; q < BAG_LEN; ++q) {
            uint32_t w = araw[b * 52 + q];
            rank += (w < v || (w == v && q < (int)i)) ? 1 : 0;
        }
        S[b * 52 + rank] = v;
    }
    __syncthreads();

    // ---- phase 2b: 4-way merge per quad via rank composition ----
    for (int p = tid; p < BAGS_PB * BAG_LEN; p += NTHR) {
        uint32_t bag = (uint32_t)p / 50u;
        uint32_t i   = (uint32_t)p - bag * 50u;
        uint32_t qd  = bag >> 2, b = bag & 3u;
        uint32_t v = S[bag * 52 + i];
        int r = (int)i;
        for (uint32_t b2 = 0; b2 < 4u; ++b2) {
            if (b2 == b) continue;
            const uint32_t* T = &S[((qd << 2) + b2) * 52];
            uint32_t key = (b2 < b) ? v + 1u : v;  // tie-break by bag id
            int lo = 0, hi = 50;
            while (lo < hi) {                      // ~6 uniform steps
                int mid = (lo + hi) >> 1;
                bool lt = T[mid] < key;
                lo = lt ? mid + 1 : lo;
                hi = lt ? hi : mid;
            }
            r += lo;
        }
        extq[qd][r]       = (v << 2) | b;                  // first copy
        extq[qd][r + 200] = ((v + (uint32_t)WS) << 2) | b; // rotation copy
    }
    __syncthreads();                       // ext final; S/araw dead

    // ---- phase 3: per-thread stream init (2 quads per thread) ----
    const uint32_t c  = ((uint32_t)d * SBIG) % (uint32_t)WS;
    const uint32_t C4 = (uint32_t)(((int)c - WS) * 4);  // 4*(c-WS) mod 2^32
    const uint32_t limit = ((uint32_t)WS - c) << 2;     // keys with v < WS-c

    uint32_t t4[2];
    float sm[2][4];
#pragma unroll
    for (int qi = 0; qi < 2; ++qi) {
        const uint32_t* eg = &extq[(g << 1) + qi][0];
        int lo = 0, hi = 200;
        while (lo < hi) {
            int mid = (lo + hi) >> 1;
            bool lt = eg[mid] < limit;
            lo = lt ? mid + 1 : lo;
            hi = lt ? hi : mid;
        }
        t4[qi] = (uint32_t)lo;             // ENTRY index into extq row
        sm[qi][0] = sm[qi][1] = sm[qi][2] = sm[qi][3] = 0.0f;
    }

    // ---- phase 4: region sweep, single 128KB bf16 tile ----
    for (int r = 0; r < NREG; ++r) {
        const int lo  = r * RSZE;
        const int len = (RSZE < WS - lo) ? RSZE : (WS - lo);  // last: 33920
        __syncthreads();                   // prev tile consumed (or ph 1-3)

        // stage bf16 region: async, 16B per lane = 8 entries, contiguous
        for (int s = tid; s < (len >> 3); s += NTHR)
            GLOAD_LDS16(wbf + lo + (s << 3), &tile[s << 3]);
        __syncthreads();                   // barrier drains vmcnt

        const uint32_t len4 = (uint32_t)len << 2;
        const uint32_t CL   = C4 - (((uint32_t)lo) << 2);
        const char* tb = (const char*)&tile[0];

#pragma unroll
        for (int qi = 0; qi < 2; ++qi) {
            const uint32_t* eg = &extq[(g << 1) + qi][0];
            uint32_t t_ = t4[qi];
            float s0 = sm[qi][0], s1 = sm[qi][1];
            float s2 = sm[qi][2], s3 = sm[qi][3];

            // current 4-key block (b128; t_ <= 400, reads reach eg[403])
            uint32_t K0 = eg[t_],     K1 = eg[t_ + 1];
            uint32_t K2 = eg[t_ + 2], K3 = eg[t_ + 3];
            uint32_t u0 = K0 + CL, u3 = K3 + CL;

            // bulk: 4 entries straight-line (monotone => all in-region)
            while (u3 < len4) {
                const uint32_t u1 = K1 + CL, u2 = K2 + CL;
                const uint32_t r0 = *(const uint16_t*)(tb + ((u0 >> 1) & ~1u));
                const uint32_t r1 = *(const uint16_t*)(tb + ((u1 >> 1) & ~1u));
                const uint32_t r2 = *(const uint16_t*)(tb + ((u2 >> 1) & ~1u));
                const uint32_t r3 = *(const uint16_t*)(tb + ((u3 >> 1) & ~1u));
                t_ += 4u;                   // next K block in flight early
                K0 = eg[t_];     K1 = eg[t_ + 1];
                K2 = eg[t_ + 2]; K3 = eg[t_ + 3];
                const float v0 = __uint_as_float(r0 << 16);
                const float v1 = __uint_as_float(r1 << 16);
                const float v2 = __uint_as_float(r2 << 16);
                const float v3 = __uint_as_float(r3 << 16);
                uint32_t tg;
                tg = u0 & 3u;
                s0 += (tg == 0u) ? v0 : 0.0f; s1 += (tg == 1u) ? v0 : 0.0f;
                s2 += (tg == 2u) ? v0 : 0.0f; s3 += (tg == 3u) ? v0 : 0.0f;
                tg = u1 & 3u;
                s0 += (tg == 0u) ? v1 : 0.0f; s1 += (tg == 1u) ? v1 : 0.0f;
                s2 += (tg == 2u) ? v1 : 0.0f; s3 += (tg == 3u) ? v1 : 0.0f;
                tg = u2 & 3u;
                s0 += (tg == 0u) ? v2 : 0.0f; s1 += (tg == 1u) ? v2 : 0.0f;
                s2 += (tg == 2u) ? v2 : 0.0f; s3 += (tg == 3u) ? v2 : 0.0f;
                tg = u3 & 3u;
                s0 += (tg == 0u) ? v3 : 0.0f; s1 += (tg == 1u) ? v3 : 0.0f;
                s2 += (tg == 2u) ? v3 : 0.0f; s3 += (tg == 3u) ? v3 : 0.0f;
                u0 = K0 + CL; u3 = K3 + CL;
            }

            // tail: <=3 remaining in-region entries, single-step
            while (u0 < len4) {
                const uint32_t raw =
                    *(const uint16_t*)(tb + ((u0 >> 1) & ~1u));
                const float v = __uint_as_float(raw << 16);
                const uint32_t tg = u0 & 3u;
                s0 += (tg == 0u) ? v : 0.0f; s1 += (tg == 1u) ? v : 0.0f;
                s2 += (tg == 2u) ? v : 0.0f; s3 += (tg == 3u) ? v : 0.0f;
                t_ += 1u;
                u0 = eg[t_] + CL;
            }

            t4[qi] = t_;
            sm[qi][0] = s0; sm[qi][1] = s1; sm[qi][2] = s2; sm[qi][3] = s3;
        }
    }

    // ---- phase 5: coalesced output (bag = 8g + 4qi + tag) ----
#pragma unroll
    for (int qi = 0; qi < 2; ++qi)
#pragma unroll
        for (int b = 0; b < 4; ++b) {
            const int bag = (g << 3) + (qi << 2) + b;
            out[(size_t)(bagBase + bag) * EMB_DIM + d] = sm[qi][b];
        }
}

// ---- fallback (ws too small): R7's proven fp32 single-tile kernel ----
#define RSIZE_FB 32768
#define NREG_FB  62
#define EXT_N    104
#define SENT4    0x10000000u

__global__ __launch_bounds__(NTHR, 4) void heb_single(
    const float* __restrict__ weight,
    const int*   __restrict__ indices,
    float*       __restrict__ out)
{
    __shared__ __align__(16) float tile[RSIZE_FB];
    __shared__ uint32_t ext4[BAGS_PB][EXT_N];
    const int tid = threadIdx.x, d = tid & 127, bag_lo = tid >> 7;
    const int bagBase = blockIdx.x * BAGS_PB;
    uint32_t* araw = (uint32_t*)&tile[0];
    for (int p = tid; p < BAGS_PB * BAG_LEN; p += NTHR) {
        uint32_t g = (uint32_t)p / 50u, i = (uint32_t)p - g * 50u;
        uint64_t idx = (uint64_t)(uint32_t)indices[bagBase * BAG_LEN + p];
        araw[g * 52 + i] = (uint32_t)((idx * 9824516537ull) % (uint64_t)WS);
    }
    __syncthreads();
    for (int p = tid; p < BAGS_PB * BAG_LEN; p += NTHR) {
        uint32_t g = (uint32_t)p / 50u, i = (uint32_t)p - g * 50u;
        uint32_t v = araw[g * 52 + i];
        int rank = 0;
        for (int q = 0; q < BAG_LEN; ++q) {
            uint32_t w = araw[g * 52 + q];
            rank += (w < v || (w == v && q < (int)i)) ? 1 : 0;
        }
        ext4[g][rank] = v << 2;
        ext4[g][rank + 50] = (v + (uint32_t)WS) << 2;
    }
    for (int p = tid; p < BAGS_PB * 4; p += NTHR)
        ext4[p >> 2][100 + (p & 3)] = SENT4;
    __syncthreads();
    const uint32_t c = ((uint32_t)d * SBIG) % (uint32_t)WS;
    const uint32_t C4 = (uint32_t)(((int)c - WS) * 4);
    const uint32_t wmc4 = ((uint32_t)WS - c) << 2;
    uint32_t t4[8], h4[8]; float sm[8];
#pragma unroll
    for (int k = 0; k < 8; ++k) {
        const uint32_t* eg = &ext4[(bag_lo << 3) + k][0];
        int nlow = 0;
        for (int q = 0; q < BAG_LEN; ++q) nlow += (eg[q] < wmc4) ? 1 : 0;
        t4[k] = (uint32_t)nlow << 2; h4[k] = eg[nlow] + C4; sm[k] = 0.0f;
    }
    for (int r = 0; r < NREG_FB; ++r) {
        const int lo = r * RSIZE_FB;
        const int len = (RSIZE_FB < WS - lo) ? RSIZE_FB : (WS - lo);
        __syncthreads();
        for (int s = tid; s < (len >> 2); s += NTHR)
            GLOAD_LDS16(weight + lo + (s << 2), &tile[s << 2]);
        __syncthreads();
        const uint32_t lo4 = ((uint32_t)lo) << 2;
        const uint32_t hi4 = (r == NREG_FB - 1) ? (uint32_t)(4 * WS)
                                                : lo4 + ((uint32_t)RSIZE_FB << 2);
        const char* tb = (const char*)&tile[0];
#pragma unroll
        for (int k = 0; k < 8; ++k) {
            const char* eg = (const char*)&ext4[(bag_lo << 3) + k][0];
            uint32_t t_ = t4[k], h_ = h4[k]; float s_ = sm[k];
            while (h_ < hi4) {
                s_ += *(const float*)(tb + (h_ - lo4));
                t_ += 4u;
                h_ = *(const uint32_t*)(eg + t_) + C4;
            }
            t4[k] = t_; h4[k] = h_; sm[k] = s_;
        }
    }
#pragma unroll
    for (int k = 0; k < 8; ++k)
        out[(size_t)(bagBase + (bag_lo << 3) + k) * EMB_DIM + d] = sm[k];
}

extern "C" void kernel_launch(void* const* d_in, const int* in_sizes, int n_in,
                              void* d_out, int out_size, void* d_ws, size_t ws_size,
                              hipStream_t stream)
{
    const float* weight  = (const float*)d_in[0];   // [2,000,000] fp32
    const int*   indices = (const int*)d_in[1];     // [16384*50] int
    float*       out     = (float*)d_out;           // [16384*128] fp32

    if (ws_size >= (size_t)WS * sizeof(uint16_t)) {
        uint16_t* wbf = (uint16_t*)d_ws;
        conv_bf16<<<(WS / 8 + 255) / 256, 256, 0, stream>>>(weight, wbf);
        heb_bf16b<<<NBLK, NTHR, 0, stream>>>(wbf, indices, out);
    } else {
        heb_single<<<NBLK, NTHR, 0, stream>>>(weight, indices, out);
    }
}